// Round 2
// baseline (1088.313 us; speedup 1.0000x reference)
//
#include <hip/hip_runtime.h>

#define Nn 100000
#define Tt 16
#define Dd 8
#define Hh 40
#define HP1 41
#define XE 50      // Xe = [h0..h39, 1, x0..x7, y]
#define NPAIR 1275 // 50*51/2 symmetric pairs
#define NPADDED 1280
#define NB 64
#define NTILES ((Nn + NB - 1) / NB)
#define GRID1 512

// output offsets (flat, return order)
#define OFF_BG1   0
#define OFF_BG2   16
#define OFF_MU    32
#define OFF_KAPPA 160
#define OFF_NU    176
#define OFF_PSI   192
#define OFF_WM    1216
#define OFF_WS    1872
#define OFF_ZA    28768
#define OFF_ZB    28784
#define OFF_EA    28800
#define OFF_EB    28816

__device__ __forceinline__ int pidx(int i, int j) {
  if (i > j) { int tmp = i; i = j; j = tmp; }
  return (i * (2 * XE - i + 1)) / 2 + (j - i);  // = 50i - i(i-1)/2 + (j-i)
}

__global__ void zero_ws_kernel(float* ws, int n) {
  int i = blockIdx.x * blockDim.x + threadIdx.x;
  if (i < n) ws[i] = 0.f;
}

// ---------------- Kernel 1: weighted Gram reduction ----------------
__global__ __launch_bounds__(256, 2)
void gram_reduce(const float* __restrict__ Phi, const float* __restrict__ Xd,
                 const float* __restrict__ Yd, const float* __restrict__ Welm,
                 const float* __restrict__ belm, float* __restrict__ acc_ws)
{
  __shared__ float sW[Dd * Hh];
  __shared__ float sb[Hh];
  __shared__ float Xs[NB][XE];
  __shared__ float Ps[NB][Tt];

  int tid = threadIdx.x;
  for (int i = tid; i < Dd * Hh; i += 256) sW[i] = Welm[i];
  if (tid < Hh) sb[tid] = belm[tid];

  // pair ownership: up to 5 pairs per thread (all statically indexed!)
  int pi_r[5], pj_r[5];
  bool pv_r[5];
#pragma unroll
  for (int k = 0; k < 5; ++k) {
    int p = tid + k * 256;
    if (p < NPAIR) {
      int i = 0, s = 0;
      while (s + (XE - i) <= p) { s += XE - i; ++i; }
      pi_r[k] = i; pj_r[k] = i + (p - s); pv_r[k] = true;
    } else { pi_r[k] = 0; pj_r[k] = 0; pv_r[k] = false; }
  }

  float acc[5][Tt];
#pragma unroll
  for (int k = 0; k < 5; ++k)
#pragma unroll
    for (int t = 0; t < Tt; ++t) acc[k][t] = 0.f;

  for (int tile = blockIdx.x; tile < NTILES; tile += gridDim.x) {
    int n0 = tile * NB;
    __syncthreads();  // protect Xs/Ps from prior iteration readers
    // stage phi (coalesced: Phi is row-major N x 16)
    for (int idx = tid; idx < NB * Tt; idx += 256) {
      int n = idx / Tt, t = idx % Tt;
      int gn = n0 + n;
      Ps[n][t] = (gn < Nn) ? Phi[gn * Tt + t] : 0.f;
    }
    // stage x
    for (int idx = tid; idx < NB * Dd; idx += 256) {
      int n = idx / Dd, d = idx % Dd;
      int gn = n0 + n;
      Xs[n][41 + d] = (gn < Nn) ? Xd[gn * Dd + d] : 0.f;
    }
    // stage y + constant column
    for (int n = tid; n < NB; n += 256) {
      int gn = n0 + n;
      Xs[n][49] = (gn < Nn) ? Yd[gn] : 0.f;
      Xs[n][40] = 1.f;
    }
    __syncthreads();
    // ELM hidden layer: h = sigmoid(x W + b)
    for (int idx = tid; idx < NB * Hh; idx += 256) {
      int n = idx / Hh, h = idx % Hh;
      float z = sb[h];
#pragma unroll
      for (int d = 0; d < Dd; ++d) z += Xs[n][41 + d] * sW[d * Hh + h];
      Xs[n][h] = 1.f / (1.f + __expf(-z));
    }
    __syncthreads();
    // accumulate: acc[p][t] += phi[n][t] * Xe[n][i] * Xe[n][j]
    for (int n = 0; n < NB; ++n) {
      float ph[Tt];
#pragma unroll
      for (int t = 0; t < Tt; ++t) ph[t] = Ps[n][t];  // LDS broadcast
#pragma unroll
      for (int k = 0; k < 5; ++k) {
        float prod = Xs[n][pi_r[k]] * Xs[n][pj_r[k]];
#pragma unroll
        for (int t = 0; t < Tt; ++t) acc[k][t] = fmaf(prod, ph[t], acc[k][t]);
      }
    }
  }
  // flush partials — FULLY UNROLLED so acc[][] stays in VGPRs
#pragma unroll
  for (int k = 0; k < 5; ++k) {
    if (pv_r[k]) {
      int p = tid + k * 256;
#pragma unroll
      for (int t = 0; t < Tt; ++t) atomicAdd(&acc_ws[p * Tt + t], acc[k][t]);
    }
  }
}

// ---------------- Kernel 2: per-t inversion + all small outputs ----------------
__global__ __launch_bounds__(256)
void finalize_kernel(const float* __restrict__ acc, const float* __restrict__ epsA,
                     const float* __restrict__ epsB, const float* __restrict__ zetA,
                     const float* __restrict__ zetB, float* __restrict__ out)
{
  int t = blockIdx.x;
  int tid = threadIdx.x;
  __shared__ float G[HP1][2 * HP1 + 2];   // augmented [M | I] -> [junk | WS]
  __shared__ float As[HP1][HP1 + 1];
  __shared__ float bs[HP1];
  __shared__ float colk[HP1];
  __shared__ float red[256];
  __shared__ float wmv[HP1];
  __shared__ float mus[Dd];
  __shared__ float pivinv_s;

  float epsExp = epsA[t] / epsB[t];
  float zetaExp = zetA[t] / zetB[t];

  for (int idx = tid; idx < HP1 * HP1; idx += 256) {
    int i = idx / HP1, j = idx % HP1;
    float a = acc[pidx(i, j) * Tt + t];
    As[i][j] = a;
    G[i][j] = epsExp * a + (i == j ? zetaExp : 0.f);
    G[i][HP1 + j] = (i == j) ? 1.f : 0.f;
  }
  if (tid < HP1) bs[tid] = acc[pidx(tid, 49) * Tt + t];
  __syncthreads();

  // Gauss-Jordan (SPD, no pivoting)
  for (int k = 0; k < HP1; ++k) {
    if (tid == 0) pivinv_s = 1.f / G[k][k];
    __syncthreads();
    float pivinv = pivinv_s;
    for (int j = tid; j < 2 * HP1; j += 256) G[k][j] *= pivinv;
    if (tid < HP1) colk[tid] = (tid == k) ? 0.f : G[tid][k];
    __syncthreads();
    for (int idx = tid; idx < HP1 * 2 * HP1; idx += 256) {
      int i = idx / (2 * HP1), j = idx % (2 * HP1);
      if (i != k) G[i][j] -= colk[i] * G[k][j];
    }
    __syncthreads();
  }

  // write WS
  for (int idx = tid; idx < HP1 * HP1; idx += 256) {
    int i = idx / HP1, j = idx % HP1;
    out[OFF_WS + (t * HP1 + i) * HP1 + j] = G[i][HP1 + j];
  }
  // WMv = zetaExp * WS @ b
  if (tid < HP1) {
    float s = 0.f;
    for (int j = 0; j < HP1; ++j) s += G[tid][HP1 + j] * bs[j];
    float w = zetaExp * s;
    wmv[tid] = w;
    out[OFF_WM + t * HP1 + tid] = w;
  }
  __syncthreads();
  // t2 = sum_ij A_ij * WS_ij  (both symmetric)
  float lt2 = 0.f;
  for (int idx = tid; idx < HP1 * HP1; idx += 256) {
    int i = idx / HP1, j = idx % HP1;
    lt2 += As[i][j] * G[i][HP1 + j];
  }
  red[tid] = lt2; __syncthreads();
  for (int s = 128; s > 0; s >>= 1) {
    if (tid < s) red[tid] += red[tid + s];
    __syncthreads();
  }
  float t2v = red[0];

  float sp = acc[pidx(40, 40) * Tt + t];  // sumPhi[t]
  float kap = 1000.f + sp;

  if (tid == 0) {
    float trWS = 0.f, wn = 0.f;
    for (int i = 0; i < HP1; ++i) { trWS += G[i][HP1 + i]; wn += wmv[i] * wmv[i]; }
    out[OFF_BG1 + t] = 1.f + sp;
    float rest = 0.f;
    for (int u = t + 1; u < Tt; ++u) rest += acc[pidx(40, 40) * Tt + u];
    out[OFF_BG2 + t] = 1.f + rest;            // ALPHA_DP = 1
    out[OFF_KAPPA + t] = kap;
    out[OFF_NU + t] = sp + 100.f;             // sumPhi + NU0
    out[OFF_ZA + t] = zetA[t] + 0.5f * (float)HP1;
    out[OFF_ZB + t] = zetB[t] + 0.5f * (wn + trWS);
    out[OFF_EA + t] = epsA[t] + 0.5f * sp;
    out[OFF_EB + t] = epsB[t] + 0.5f * t2v;   // kernel 3 atomically adds 0.5*t1
  }
  // mu
  if (tid < Dd) {
    float m = acc[pidx(40, 41 + tid) * Tt + t] / kap;
    mus[tid] = m;
    out[OFF_MU + tid * Tt + t] = m;
  }
  __syncthreads();
  // psi = 500*I + S - kappa * mu mu^T
  if (tid < Dd * Dd) {
    int i = tid / Dd, j = tid % Dd;
    float S = acc[pidx(41 + i, 41 + j) * Tt + t];
    float v = (i == j ? 500.f : 0.f) + S - kap * mus[i] * mus[j];
    out[OFF_PSI + (i * Dd + j) * Tt + t] = v;
  }
}

// ---------------- Kernel 3: t1 = sum_n phi * err^2 ----------------
__global__ __launch_bounds__(256)
void resid_kernel(const float* __restrict__ Phi, const float* __restrict__ Xd,
                  const float* __restrict__ Yd, const float* __restrict__ Welm,
                  const float* __restrict__ belm, float* __restrict__ out)
{
  __shared__ float sW[Dd * Hh];
  __shared__ float sb[Hh];
  __shared__ float sWM[Tt][HP1];
  __shared__ float red[256];
  int tid = threadIdx.x;
  for (int i = tid; i < Dd * Hh; i += 256) sW[i] = Welm[i];
  if (tid < Hh) sb[tid] = belm[tid];
  for (int i = tid; i < Tt * HP1; i += 256) sWM[i / HP1][i % HP1] = out[OFF_WM + i];
  __syncthreads();

  float acc[Tt];
#pragma unroll
  for (int t = 0; t < Tt; ++t) acc[t] = 0.f;

  int stride = gridDim.x * blockDim.x;
  for (int n = blockIdx.x * blockDim.x + tid; n < Nn; n += stride) {
    float x[Dd];
#pragma unroll
    for (int d = 0; d < Dd; ++d) x[d] = Xd[n * Dd + d];
    float y = Yd[n];
    float h[HP1];
#pragma unroll
    for (int hh = 0; hh < Hh; ++hh) {
      float z = sb[hh];
#pragma unroll
      for (int d = 0; d < Dd; ++d) z += x[d] * sW[d * Hh + hh];
      h[hh] = 1.f / (1.f + __expf(-z));
    }
    h[40] = 1.f;
#pragma unroll
    for (int t = 0; t < Tt; ++t) {
      float pred = 0.f;
#pragma unroll
      for (int i = 0; i < HP1; ++i) pred += h[i] * sWM[t][i];
      float e = y - pred;
      acc[t] += e * e * Phi[n * Tt + t];
    }
  }
  // FULLY UNROLLED so acc[] stays in VGPRs
#pragma unroll
  for (int t = 0; t < Tt; ++t) {
    red[tid] = acc[t]; __syncthreads();
    for (int s = 128; s > 0; s >>= 1) {
      if (tid < s) red[tid] += red[tid + s];
      __syncthreads();
    }
    if (tid == 0) atomicAdd(&out[OFF_EB + t], 0.5f * red[0]);
    __syncthreads();
  }
}

extern "C" void kernel_launch(void* const* d_in, const int* in_sizes, int n_in,
                              void* d_out, int out_size, void* d_ws, size_t ws_size,
                              hipStream_t stream) {
  const float* Phi = (const float*)d_in[1];
  const float* Xd  = (const float*)d_in[2];
  const float* Yd  = (const float*)d_in[3];
  const float* W   = (const float*)d_in[4];
  const float* bb  = (const float*)d_in[5];
  const float* eA  = (const float*)d_in[6];
  const float* eB  = (const float*)d_in[7];
  const float* zA  = (const float*)d_in[8];
  const float* zB  = (const float*)d_in[9];
  float* out = (float*)d_out;
  float* ws  = (float*)d_ws;

  int nacc = NPADDED * Tt;  // 20480 floats
  hipLaunchKernelGGL(zero_ws_kernel, dim3((nacc + 511) / 512), dim3(512), 0, stream, ws, nacc);
  hipLaunchKernelGGL(gram_reduce, dim3(GRID1), dim3(256), 0, stream, Phi, Xd, Yd, W, bb, ws);
  hipLaunchKernelGGL(finalize_kernel, dim3(Tt), dim3(256), 0, stream, ws, eA, eB, zA, zB, out);
  hipLaunchKernelGGL(resid_kernel, dim3(256), dim3(256), 0, stream, Phi, Xd, Yd, W, bb, out);
}

// Round 3
// 1079.209 us; speedup vs baseline: 1.0084x; 1.0084x over previous
//
#include <hip/hip_runtime.h>

#define Nn 100000
#define Tt 16
#define Dd 8
#define Hh 40
#define HP1 41
#define XE 50      // Xe = [h0..h39, 1, x0..x7, y]
#define NPAIR 1275 // 50*51/2 symmetric pairs
#define NPADDED 1280
#define NB 64
#define NTILES ((Nn + NB - 1) / NB)
#define GRID1 512

// output offsets (flat, return order)
#define OFF_BG1   0
#define OFF_BG2   16
#define OFF_MU    32
#define OFF_KAPPA 160
#define OFF_NU    176
#define OFF_PSI   192
#define OFF_WM    1216
#define OFF_WS    1872
#define OFF_ZA    28768
#define OFF_ZB    28784
#define OFF_EA    28800
#define OFF_EB    28816

typedef float v16f __attribute__((ext_vector_type(16)));

__device__ __forceinline__ int pidx(int i, int j) {
  if (i > j) { int tmp = i; i = j; j = tmp; }
  return (i * (2 * XE - i + 1)) / 2 + (j - i);
}

__device__ __forceinline__ bool decode_pair(int p, int& ii, int& jj) {
  if (p >= NPAIR) { ii = 0; jj = 0; return false; }
  int i = 0, s = 0;
  while (s + (XE - i) <= p) { s += XE - i; ++i; }
  ii = i; jj = i + (p - s); return true;
}

__global__ void zero_ws_kernel(float* ws, int n) {
  int i = blockIdx.x * blockDim.x + threadIdx.x;
  if (i < n) ws[i] = 0.f;
}

// ---------------- Kernel 1: weighted Gram reduction ----------------
// acc lives in five ext_vector SSA values -> cannot be demoted to scratch.
__global__ __launch_bounds__(256, 2)
void gram_reduce(const float* __restrict__ Phi, const float* __restrict__ Xd,
                 const float* __restrict__ Yd, const float* __restrict__ Welm,
                 const float* __restrict__ belm, float* __restrict__ acc_ws)
{
  __shared__ float sW[Dd * Hh];
  __shared__ float sb[Hh];
  __shared__ float Xs[NB][XE];
  __shared__ __align__(64) float Ps[NB][Tt];

  int tid = threadIdx.x;
  for (int i = tid; i < Dd * Hh; i += 256) sW[i] = Welm[i];
  if (tid < Hh) sb[tid] = belm[tid];

  int i0, j0, i1, j1, i2, j2, i3, j3, i4, j4;
  bool v0 = decode_pair(tid,            i0, j0);
  bool v1 = decode_pair(tid + 256,      i1, j1);
  bool v2 = decode_pair(tid + 512,      i2, j2);
  bool v3 = decode_pair(tid + 768,      i3, j3);
  bool v4 = decode_pair(tid + 1024,     i4, j4);

  v16f A0 = {}, A1 = {}, A2 = {}, A3 = {}, A4 = {};

  for (int tile = blockIdx.x; tile < NTILES; tile += gridDim.x) {
    int n0 = tile * NB;
    __syncthreads();  // protect Xs/Ps from prior iteration readers
    // stage phi (coalesced: Phi is row-major N x 16)
    for (int idx = tid; idx < NB * Tt; idx += 256) {
      int n = idx / Tt, t = idx % Tt;
      int gn = n0 + n;
      Ps[n][t] = (gn < Nn) ? Phi[gn * Tt + t] : 0.f;
    }
    // stage x
    for (int idx = tid; idx < NB * Dd; idx += 256) {
      int n = idx / Dd, d = idx % Dd;
      int gn = n0 + n;
      Xs[n][41 + d] = (gn < Nn) ? Xd[gn * Dd + d] : 0.f;
    }
    // stage y + constant column
    for (int n = tid; n < NB; n += 256) {
      int gn = n0 + n;
      Xs[n][49] = (gn < Nn) ? Yd[gn] : 0.f;
      Xs[n][40] = 1.f;
    }
    __syncthreads();
    // ELM hidden layer: h = sigmoid(x W + b)
    for (int idx = tid; idx < NB * Hh; idx += 256) {
      int n = idx / Hh, h = idx % Hh;
      float z = sb[h];
#pragma unroll
      for (int d = 0; d < Dd; ++d) z += Xs[n][41 + d] * sW[d * Hh + h];
      Xs[n][h] = 1.f / (1.f + __expf(-z));
    }
    __syncthreads();
    // accumulate: acc[p][t] += phi[n][t] * Xe[n][i] * Xe[n][j]
    for (int n = 0; n < NB; ++n) {
      v16f ph = *(const v16f*)(&Ps[n][0]);  // 64B broadcast read, conflict-free
      float p0 = Xs[n][i0] * Xs[n][j0];
      float p1 = Xs[n][i1] * Xs[n][j1];
      float p2 = Xs[n][i2] * Xs[n][j2];
      float p3 = Xs[n][i3] * Xs[n][j3];
      float p4 = Xs[n][i4] * Xs[n][j4];
#pragma unroll
      for (int t = 0; t < Tt; ++t) {
        A0[t] = fmaf(p0, ph[t], A0[t]);
        A1[t] = fmaf(p1, ph[t], A1[t]);
        A2[t] = fmaf(p2, ph[t], A2[t]);
        A3[t] = fmaf(p3, ph[t], A3[t]);
        A4[t] = fmaf(p4, ph[t], A4[t]);
      }
    }
  }
  // flush partials (constant-index vector extracts)
  if (v0) {
    int p = tid;
#pragma unroll
    for (int t = 0; t < Tt; ++t) atomicAdd(&acc_ws[p * Tt + t], A0[t]);
  }
  if (v1) {
    int p = tid + 256;
#pragma unroll
    for (int t = 0; t < Tt; ++t) atomicAdd(&acc_ws[p * Tt + t], A1[t]);
  }
  if (v2) {
    int p = tid + 512;
#pragma unroll
    for (int t = 0; t < Tt; ++t) atomicAdd(&acc_ws[p * Tt + t], A2[t]);
  }
  if (v3) {
    int p = tid + 768;
#pragma unroll
    for (int t = 0; t < Tt; ++t) atomicAdd(&acc_ws[p * Tt + t], A3[t]);
  }
  if (v4) {
    int p = tid + 1024;
#pragma unroll
    for (int t = 0; t < Tt; ++t) atomicAdd(&acc_ws[p * Tt + t], A4[t]);
  }
}

// ---------------- Kernel 2: per-t inversion + all small outputs ----------------
__global__ __launch_bounds__(256)
void finalize_kernel(const float* __restrict__ acc, const float* __restrict__ epsA,
                     const float* __restrict__ epsB, const float* __restrict__ zetA,
                     const float* __restrict__ zetB, float* __restrict__ out)
{
  int t = blockIdx.x;
  int tid = threadIdx.x;
  __shared__ float G[HP1][2 * HP1 + 2];   // augmented [M | I] -> [junk | WS]
  __shared__ float As[HP1][HP1 + 1];
  __shared__ float bs[HP1];
  __shared__ float colk[HP1];
  __shared__ float red[256];
  __shared__ float wmv[HP1];
  __shared__ float mus[Dd];
  __shared__ float pivinv_s;

  float epsExp = epsA[t] / epsB[t];
  float zetaExp = zetA[t] / zetB[t];

  for (int idx = tid; idx < HP1 * HP1; idx += 256) {
    int i = idx / HP1, j = idx % HP1;
    float a = acc[pidx(i, j) * Tt + t];
    As[i][j] = a;
    G[i][j] = epsExp * a + (i == j ? zetaExp : 0.f);
    G[i][HP1 + j] = (i == j) ? 1.f : 0.f;
  }
  if (tid < HP1) bs[tid] = acc[pidx(tid, 49) * Tt + t];
  __syncthreads();

  // Gauss-Jordan (SPD, no pivoting)
  for (int k = 0; k < HP1; ++k) {
    if (tid == 0) pivinv_s = 1.f / G[k][k];
    __syncthreads();
    float pivinv = pivinv_s;
    for (int j = tid; j < 2 * HP1; j += 256) G[k][j] *= pivinv;
    if (tid < HP1) colk[tid] = (tid == k) ? 0.f : G[tid][k];
    __syncthreads();
    for (int idx = tid; idx < HP1 * 2 * HP1; idx += 256) {
      int i = idx / (2 * HP1), j = idx % (2 * HP1);
      if (i != k) G[i][j] -= colk[i] * G[k][j];
    }
    __syncthreads();
  }

  // write WS
  for (int idx = tid; idx < HP1 * HP1; idx += 256) {
    int i = idx / HP1, j = idx % HP1;
    out[OFF_WS + (t * HP1 + i) * HP1 + j] = G[i][HP1 + j];
  }
  // WMv = zetaExp * WS @ b
  if (tid < HP1) {
    float s = 0.f;
    for (int j = 0; j < HP1; ++j) s += G[tid][HP1 + j] * bs[j];
    float w = zetaExp * s;
    wmv[tid] = w;
    out[OFF_WM + t * HP1 + tid] = w;
  }
  __syncthreads();
  // t2 = sum_ij A_ij * WS_ij  (both symmetric)
  float lt2 = 0.f;
  for (int idx = tid; idx < HP1 * HP1; idx += 256) {
    int i = idx / HP1, j = idx % HP1;
    lt2 += As[i][j] * G[i][HP1 + j];
  }
  red[tid] = lt2; __syncthreads();
  for (int s = 128; s > 0; s >>= 1) {
    if (tid < s) red[tid] += red[tid + s];
    __syncthreads();
  }
  float t2v = red[0];

  float sp = acc[pidx(40, 40) * Tt + t];  // sumPhi[t]
  float kap = 1000.f + sp;

  if (tid == 0) {
    float trWS = 0.f, wn = 0.f;
    for (int i = 0; i < HP1; ++i) { trWS += G[i][HP1 + i]; wn += wmv[i] * wmv[i]; }
    out[OFF_BG1 + t] = 1.f + sp;
    float rest = 0.f;
    for (int u = t + 1; u < Tt; ++u) rest += acc[pidx(40, 40) * Tt + u];
    out[OFF_BG2 + t] = 1.f + rest;            // ALPHA_DP = 1
    out[OFF_KAPPA + t] = kap;
    out[OFF_NU + t] = sp + 100.f;             // sumPhi + NU0
    out[OFF_ZA + t] = zetA[t] + 0.5f * (float)HP1;
    out[OFF_ZB + t] = zetB[t] + 0.5f * (wn + trWS);
    out[OFF_EA + t] = epsA[t] + 0.5f * sp;
    out[OFF_EB + t] = epsB[t] + 0.5f * t2v;   // kernel 3 atomically adds 0.5*t1
  }
  // mu
  if (tid < Dd) {
    float m = acc[pidx(40, 41 + tid) * Tt + t] / kap;
    mus[tid] = m;
    out[OFF_MU + tid * Tt + t] = m;
  }
  __syncthreads();
  // psi = 500*I + S - kappa * mu mu^T
  if (tid < Dd * Dd) {
    int i = tid / Dd, j = tid % Dd;
    float S = acc[pidx(41 + i, 41 + j) * Tt + t];
    float v = (i == j ? 500.f : 0.f) + S - kap * mus[i] * mus[j];
    out[OFF_PSI + (i * Dd + j) * Tt + t] = v;
  }
}

// ---------------- Kernel 3: t1 = sum_n phi * err^2 ----------------
__global__ __launch_bounds__(256)
void resid_kernel(const float* __restrict__ Phi, const float* __restrict__ Xd,
                  const float* __restrict__ Yd, const float* __restrict__ Welm,
                  const float* __restrict__ belm, float* __restrict__ out)
{
  __shared__ float sW[Dd * Hh];
  __shared__ float sb[Hh];
  __shared__ float sWM[Tt][HP1];
  __shared__ float red[256];
  int tid = threadIdx.x;
  for (int i = tid; i < Dd * Hh; i += 256) sW[i] = Welm[i];
  if (tid < Hh) sb[tid] = belm[tid];
  for (int i = tid; i < Tt * HP1; i += 256) sWM[i / HP1][i % HP1] = out[OFF_WM + i];
  __syncthreads();

  v16f acc = {};

  int stride = gridDim.x * blockDim.x;
  for (int n = blockIdx.x * blockDim.x + tid; n < Nn; n += stride) {
    float x[Dd];
#pragma unroll
    for (int d = 0; d < Dd; ++d) x[d] = Xd[n * Dd + d];
    float y = Yd[n];
    float h[HP1];
#pragma unroll
    for (int hh = 0; hh < Hh; ++hh) {
      float z = sb[hh];
#pragma unroll
      for (int d = 0; d < Dd; ++d) z += x[d] * sW[d * Hh + hh];
      h[hh] = 1.f / (1.f + __expf(-z));
    }
    h[40] = 1.f;
#pragma unroll
    for (int t = 0; t < Tt; ++t) {
      float pred = 0.f;
#pragma unroll
      for (int i = 0; i < HP1; ++i) pred += h[i] * sWM[t][i];
      float e = y - pred;
      acc[t] = fmaf(e * e, Phi[n * Tt + t], acc[t]);
    }
  }
#pragma unroll
  for (int t = 0; t < Tt; ++t) {
    red[tid] = acc[t]; __syncthreads();
    for (int s = 128; s > 0; s >>= 1) {
      if (tid < s) red[tid] += red[tid + s];
      __syncthreads();
    }
    if (tid == 0) atomicAdd(&out[OFF_EB + t], 0.5f * red[0]);
    __syncthreads();
  }
}

extern "C" void kernel_launch(void* const* d_in, const int* in_sizes, int n_in,
                              void* d_out, int out_size, void* d_ws, size_t ws_size,
                              hipStream_t stream) {
  const float* Phi = (const float*)d_in[1];
  const float* Xd  = (const float*)d_in[2];
  const float* Yd  = (const float*)d_in[3];
  const float* W   = (const float*)d_in[4];
  const float* bb  = (const float*)d_in[5];
  const float* eA  = (const float*)d_in[6];
  const float* eB  = (const float*)d_in[7];
  const float* zA  = (const float*)d_in[8];
  const float* zB  = (const float*)d_in[9];
  float* out = (float*)d_out;
  float* ws  = (float*)d_ws;

  int nacc = NPADDED * Tt;  // 20480 floats
  hipLaunchKernelGGL(zero_ws_kernel, dim3((nacc + 511) / 512), dim3(512), 0, stream, ws, nacc);
  hipLaunchKernelGGL(gram_reduce, dim3(GRID1), dim3(256), 0, stream, Phi, Xd, Yd, W, bb, ws);
  hipLaunchKernelGGL(finalize_kernel, dim3(Tt), dim3(256), 0, stream, ws, eA, eB, zA, zB, out);
  hipLaunchKernelGGL(resid_kernel, dim3(256), dim3(256), 0, stream, Phi, Xd, Yd, W, bb, out);
}

// Round 4
// 497.277 us; speedup vs baseline: 2.1885x; 2.1702x over previous
//
#include <hip/hip_runtime.h>

#define Nn 100000
#define Tt 16
#define Dd 8
#define Hh 40
#define HP1 41
#define XE 50      // Xe = [h0..h39, 1, x0..x7, y]
#define NPAIR 1275 // 50*51/2 symmetric pairs
#define NPADDED 1280
#define NB 64
#define NTILES ((Nn + NB - 1) / NB)
#define GRID1 256
#define THR1 512
#define SLAB (NPADDED * Tt)   // 20480 floats per block-slab
#define SLABS GRID1           // 256 slabs -> 21 MB in d_ws + 80KB reduced region

// output offsets (flat, return order)
#define OFF_BG1   0
#define OFF_BG2   16
#define OFF_MU    32
#define OFF_KAPPA 160
#define OFF_NU    176
#define OFF_PSI   192
#define OFF_WM    1216
#define OFF_WS    1872
#define OFF_ZA    28768
#define OFF_ZB    28784
#define OFF_EA    28800
#define OFF_EB    28816

typedef float v16f __attribute__((ext_vector_type(16)));

__device__ __forceinline__ int pidx(int i, int j) {
  if (i > j) { int tmp = i; i = j; j = tmp; }
  return (i * (2 * XE - i + 1)) / 2 + (j - i);
}

__device__ __forceinline__ bool decode_pair(int p, int& ii, int& jj) {
  if (p >= NPAIR) { ii = 0; jj = 0; return false; }
  int i = 0, s = 0;
  while (s + (XE - i) <= p) { s += XE - i; ++i; }
  ii = i; jj = i + (p - s); return true;
}

// ---------------- Kernel 1: weighted Gram reduction (no atomics) ----------------
__global__ __launch_bounds__(THR1, 2)
void gram_reduce(const float* __restrict__ Phi, const float* __restrict__ Xd,
                 const float* __restrict__ Yd, const float* __restrict__ Welm,
                 const float* __restrict__ belm, float* __restrict__ ws)
{
  __shared__ float sW[Dd * Hh];
  __shared__ float sb[Hh];
  __shared__ float Xs[NB][XE];
  __shared__ __align__(64) float Ps[NB][Tt];

  int tid = threadIdx.x;
  for (int i = tid; i < Dd * Hh; i += THR1) sW[i] = Welm[i];
  if (tid < Hh) sb[tid] = belm[tid];

  // 3 pair-chunks per thread: p = tid, tid+512, tid+1024
  int i0, j0, i1, j1, i2, j2;
  bool v0 = decode_pair(tid,            i0, j0);
  bool v1 = decode_pair(tid + THR1,     i1, j1);
  bool v2 = decode_pair(tid + 2 * THR1, i2, j2);

  v16f A0 = {}, A1 = {}, A2 = {};

  for (int tile = blockIdx.x; tile < NTILES; tile += gridDim.x) {
    int n0 = tile * NB;
    __syncthreads();  // protect Xs/Ps from prior iteration readers
    // stage phi (coalesced: Phi is row-major N x 16)
    for (int idx = tid; idx < NB * Tt; idx += THR1) {
      int n = idx / Tt, t = idx % Tt;
      int gn = n0 + n;
      Ps[n][t] = (gn < Nn) ? Phi[gn * Tt + t] : 0.f;
    }
    // stage x
    for (int idx = tid; idx < NB * Dd; idx += THR1) {
      int n = idx / Dd, d = idx % Dd;
      int gn = n0 + n;
      Xs[n][41 + d] = (gn < Nn) ? Xd[gn * Dd + d] : 0.f;
    }
    // stage y + constant column
    for (int n = tid; n < NB; n += THR1) {
      int gn = n0 + n;
      Xs[n][49] = (gn < Nn) ? Yd[gn] : 0.f;
      Xs[n][40] = 1.f;
    }
    __syncthreads();
    // ELM hidden layer: h = sigmoid(x W + b)
    for (int idx = tid; idx < NB * Hh; idx += THR1) {
      int n = idx / Hh, h = idx % Hh;
      float z = sb[h];
#pragma unroll
      for (int d = 0; d < Dd; ++d) z += Xs[n][41 + d] * sW[d * Hh + h];
      Xs[n][h] = 1.f / (1.f + __expf(-z));
    }
    __syncthreads();
    // accumulate: acc[p][t] += phi[n][t] * Xe[n][i] * Xe[n][j]
    for (int n = 0; n < NB; ++n) {
      v16f ph = *(const v16f*)(&Ps[n][0]);  // 64B broadcast read
      float p0 = Xs[n][i0] * Xs[n][j0];
      float p1 = Xs[n][i1] * Xs[n][j1];
      float p2 = Xs[n][i2] * Xs[n][j2];
#pragma unroll
      for (int t = 0; t < Tt; ++t) {
        A0[t] = fmaf(p0, ph[t], A0[t]);
        A1[t] = fmaf(p1, ph[t], A1[t]);
        A2[t] = fmaf(p2, ph[t], A2[t]);
      }
    }
  }
  // flush partials: plain coalesced 64B vector stores into this block's slab
  float* slab = ws + (size_t)blockIdx.x * SLAB;
  if (v0) *(v16f*)(slab + (size_t)tid * Tt) = A0;
  if (v1) *(v16f*)(slab + (size_t)(tid + THR1) * Tt) = A1;
  if (v2) *(v16f*)(slab + (size_t)(tid + 2 * THR1) * Tt) = A2;
}

// ---------------- Kernel 1b: reduce slabs ----------------
__global__ __launch_bounds__(256)
void reduce_slabs(const float* __restrict__ ws, float* __restrict__ accout)
{
  int idx = blockIdx.x * 256 + threadIdx.x;
  if (idx >= NPAIR * Tt) return;
  float s = 0.f;
#pragma unroll 8
  for (int b = 0; b < SLABS; ++b) s += ws[(size_t)b * SLAB + idx];
  accout[idx] = s;
}

// ---------------- Kernel 2: per-t inversion + all small outputs ----------------
__global__ __launch_bounds__(256)
void finalize_kernel(const float* __restrict__ acc, const float* __restrict__ epsA,
                     const float* __restrict__ epsB, const float* __restrict__ zetA,
                     const float* __restrict__ zetB, float* __restrict__ out)
{
  int t = blockIdx.x;
  int tid = threadIdx.x;
  __shared__ float G[HP1][2 * HP1 + 2];   // augmented [M | I] -> [junk | WS]
  __shared__ float As[HP1][HP1 + 1];
  __shared__ float bs[HP1];
  __shared__ float colk[HP1];
  __shared__ float red[256];
  __shared__ float wmv[HP1];
  __shared__ float mus[Dd];
  __shared__ float pivinv_s;

  float epsExp = epsA[t] / epsB[t];
  float zetaExp = zetA[t] / zetB[t];

  for (int idx = tid; idx < HP1 * HP1; idx += 256) {
    int i = idx / HP1, j = idx % HP1;
    float a = acc[pidx(i, j) * Tt + t];
    As[i][j] = a;
    G[i][j] = epsExp * a + (i == j ? zetaExp : 0.f);
    G[i][HP1 + j] = (i == j) ? 1.f : 0.f;
  }
  if (tid < HP1) bs[tid] = acc[pidx(tid, 49) * Tt + t];
  __syncthreads();

  // Gauss-Jordan (SPD, no pivoting)
  for (int k = 0; k < HP1; ++k) {
    if (tid == 0) pivinv_s = 1.f / G[k][k];
    __syncthreads();
    float pivinv = pivinv_s;
    for (int j = tid; j < 2 * HP1; j += 256) G[k][j] *= pivinv;
    if (tid < HP1) colk[tid] = (tid == k) ? 0.f : G[tid][k];
    __syncthreads();
    for (int idx = tid; idx < HP1 * 2 * HP1; idx += 256) {
      int i = idx / (2 * HP1), j = idx % (2 * HP1);
      if (i != k) G[i][j] -= colk[i] * G[k][j];
    }
    __syncthreads();
  }

  // write WS
  for (int idx = tid; idx < HP1 * HP1; idx += 256) {
    int i = idx / HP1, j = idx % HP1;
    out[OFF_WS + (t * HP1 + i) * HP1 + j] = G[i][HP1 + j];
  }
  // WMv = zetaExp * WS @ b
  if (tid < HP1) {
    float s = 0.f;
    for (int j = 0; j < HP1; ++j) s += G[tid][HP1 + j] * bs[j];
    float w = zetaExp * s;
    wmv[tid] = w;
    out[OFF_WM + t * HP1 + tid] = w;
  }
  __syncthreads();
  // t2 = sum_ij A_ij * WS_ij  (both symmetric)
  float lt2 = 0.f;
  for (int idx = tid; idx < HP1 * HP1; idx += 256) {
    int i = idx / HP1, j = idx % HP1;
    lt2 += As[i][j] * G[i][HP1 + j];
  }
  red[tid] = lt2; __syncthreads();
  for (int s = 128; s > 0; s >>= 1) {
    if (tid < s) red[tid] += red[tid + s];
    __syncthreads();
  }
  float t2v = red[0];

  float sp = acc[pidx(40, 40) * Tt + t];  // sumPhi[t]
  float kap = 1000.f + sp;

  if (tid == 0) {
    float trWS = 0.f, wn = 0.f;
    for (int i = 0; i < HP1; ++i) { trWS += G[i][HP1 + i]; wn += wmv[i] * wmv[i]; }
    out[OFF_BG1 + t] = 1.f + sp;
    float rest = 0.f;
    for (int u = t + 1; u < Tt; ++u) rest += acc[pidx(40, 40) * Tt + u];
    out[OFF_BG2 + t] = 1.f + rest;            // ALPHA_DP = 1
    out[OFF_KAPPA + t] = kap;
    out[OFF_NU + t] = sp + 100.f;             // sumPhi + NU0
    out[OFF_ZA + t] = zetA[t] + 0.5f * (float)HP1;
    out[OFF_ZB + t] = zetB[t] + 0.5f * (wn + trWS);
    out[OFF_EA + t] = epsA[t] + 0.5f * sp;
    out[OFF_EB + t] = epsB[t] + 0.5f * t2v;   // kernel 3 atomically adds 0.5*t1
  }
  // mu
  if (tid < Dd) {
    float m = acc[pidx(40, 41 + tid) * Tt + t] / kap;
    mus[tid] = m;
    out[OFF_MU + tid * Tt + t] = m;
  }
  __syncthreads();
  // psi = 500*I + S - kappa * mu mu^T
  if (tid < Dd * Dd) {
    int i = tid / Dd, j = tid % Dd;
    float S = acc[pidx(41 + i, 41 + j) * Tt + t];
    float v = (i == j ? 500.f : 0.f) + S - kap * mus[i] * mus[j];
    out[OFF_PSI + (i * Dd + j) * Tt + t] = v;
  }
}

// ---------------- Kernel 3: t1 = sum_n phi * err^2 ----------------
__global__ __launch_bounds__(256)
void resid_kernel(const float* __restrict__ Phi, const float* __restrict__ Xd,
                  const float* __restrict__ Yd, const float* __restrict__ Welm,
                  const float* __restrict__ belm, float* __restrict__ out)
{
  __shared__ float sW[Dd * Hh];
  __shared__ float sb[Hh];
  __shared__ float sWM[Tt][HP1];
  __shared__ float red[256];
  int tid = threadIdx.x;
  for (int i = tid; i < Dd * Hh; i += 256) sW[i] = Welm[i];
  if (tid < Hh) sb[tid] = belm[tid];
  for (int i = tid; i < Tt * HP1; i += 256) sWM[i / HP1][i % HP1] = out[OFF_WM + i];
  __syncthreads();

  v16f acc = {};

  int stride = gridDim.x * blockDim.x;
  for (int n = blockIdx.x * blockDim.x + tid; n < Nn; n += stride) {
    float x[Dd];
#pragma unroll
    for (int d = 0; d < Dd; ++d) x[d] = Xd[n * Dd + d];
    float y = Yd[n];
    float h[HP1];
#pragma unroll
    for (int hh = 0; hh < Hh; ++hh) {
      float z = sb[hh];
#pragma unroll
      for (int d = 0; d < Dd; ++d) z += x[d] * sW[d * Hh + hh];
      h[hh] = 1.f / (1.f + __expf(-z));
    }
    h[40] = 1.f;
#pragma unroll
    for (int t = 0; t < Tt; ++t) {
      float pred = 0.f;
#pragma unroll
      for (int i = 0; i < HP1; ++i) pred += h[i] * sWM[t][i];
      float e = y - pred;
      acc[t] = fmaf(e * e, Phi[n * Tt + t], acc[t]);
    }
  }
#pragma unroll
  for (int t = 0; t < Tt; ++t) {
    red[tid] = acc[t]; __syncthreads();
    for (int s = 128; s > 0; s >>= 1) {
      if (tid < s) red[tid] += red[tid + s];
      __syncthreads();
    }
    if (tid == 0) atomicAdd(&out[OFF_EB + t], 0.5f * red[0]);
    __syncthreads();
  }
}

extern "C" void kernel_launch(void* const* d_in, const int* in_sizes, int n_in,
                              void* d_out, int out_size, void* d_ws, size_t ws_size,
                              hipStream_t stream) {
  const float* Phi = (const float*)d_in[1];
  const float* Xd  = (const float*)d_in[2];
  const float* Yd  = (const float*)d_in[3];
  const float* W   = (const float*)d_in[4];
  const float* bb  = (const float*)d_in[5];
  const float* eA  = (const float*)d_in[6];
  const float* eB  = (const float*)d_in[7];
  const float* zA  = (const float*)d_in[8];
  const float* zB  = (const float*)d_in[9];
  float* out = (float*)d_out;
  float* ws  = (float*)d_ws;
  float* acc_red = ws + (size_t)SLABS * SLAB;  // reduced Gram lives after the slabs

  hipLaunchKernelGGL(gram_reduce, dim3(GRID1), dim3(THR1), 0, stream, Phi, Xd, Yd, W, bb, ws);
  hipLaunchKernelGGL(reduce_slabs, dim3((NPAIR * Tt + 255) / 256), dim3(256), 0, stream, ws, acc_red);
  hipLaunchKernelGGL(finalize_kernel, dim3(Tt), dim3(256), 0, stream, acc_red, eA, eB, zA, zB, out);
  hipLaunchKernelGGL(resid_kernel, dim3(256), dim3(256), 0, stream, Phi, Xd, Yd, W, bb, out);
}

// Round 5
// 297.342 us; speedup vs baseline: 3.6601x; 1.6724x over previous
//
#include <hip/hip_runtime.h>

#define Nn 100000
#define Tt 16
#define Dd 8
#define Hh 40
#define HP1 41
#define XE 50      // Xe = [h0..h39, 1, x0..x7, y]
#define NPAIR 1275 // 50*51/2 symmetric pairs
#define NPADDED 1280
#define NB 64
#define NTILES ((Nn + NB - 1) / NB)
#define GRID1 256
#define THR1 512
#define SLAB (NPADDED * Tt)   // 20480 floats per block-slab
#define SLABS GRID1           // 256 slabs -> 21 MB in d_ws + 80KB reduced region

// output offsets (flat, return order)
#define OFF_BG1   0
#define OFF_BG2   16
#define OFF_MU    32
#define OFF_KAPPA 160
#define OFF_NU    176
#define OFF_PSI   192
#define OFF_WM    1216
#define OFF_WS    1872
#define OFF_ZA    28768
#define OFF_ZB    28784
#define OFF_EA    28800
#define OFF_EB    28816

typedef float v16f __attribute__((ext_vector_type(16)));

__device__ __forceinline__ int pidx(int i, int j) {
  if (i > j) { int tmp = i; i = j; j = tmp; }
  return (i * (2 * XE - i + 1)) / 2 + (j - i);
}

__device__ __forceinline__ bool decode_pair(int p, int& ii, int& jj) {
  if (p >= NPAIR) { ii = 0; jj = 0; return false; }
  int i = 0, s = 0;
  while (s + (XE - i) <= p) { s += XE - i; ++i; }
  ii = i; jj = i + (p - s); return true;
}

// ---------------- Kernel 1: weighted Gram reduction (no atomics) ----------------
__global__ __launch_bounds__(THR1, 2)
void gram_reduce(const float* __restrict__ Phi, const float* __restrict__ Xd,
                 const float* __restrict__ Yd, const float* __restrict__ Welm,
                 const float* __restrict__ belm, float* __restrict__ ws)
{
  __shared__ float sW[Dd * Hh];
  __shared__ float sb[Hh];
  __shared__ float Xs[NB][XE];
  __shared__ __align__(64) float Ps[NB][Tt];

  int tid = threadIdx.x;
  for (int i = tid; i < Dd * Hh; i += THR1) sW[i] = Welm[i];
  if (tid < Hh) sb[tid] = belm[tid];

  // 3 pair-chunks per thread: p = tid, tid+512, tid+1024
  int i0, j0, i1, j1, i2, j2;
  bool v0 = decode_pair(tid,            i0, j0);
  bool v1 = decode_pair(tid + THR1,     i1, j1);
  bool v2 = decode_pair(tid + 2 * THR1, i2, j2);

  v16f A0 = {}, A1 = {}, A2 = {};

  for (int tile = blockIdx.x; tile < NTILES; tile += gridDim.x) {
    int n0 = tile * NB;
    __syncthreads();  // protect Xs/Ps from prior iteration readers
    // stage phi (coalesced: Phi is row-major N x 16)
    for (int idx = tid; idx < NB * Tt; idx += THR1) {
      int n = idx / Tt, t = idx % Tt;
      int gn = n0 + n;
      Ps[n][t] = (gn < Nn) ? Phi[gn * Tt + t] : 0.f;
    }
    // stage x
    for (int idx = tid; idx < NB * Dd; idx += THR1) {
      int n = idx / Dd, d = idx % Dd;
      int gn = n0 + n;
      Xs[n][41 + d] = (gn < Nn) ? Xd[gn * Dd + d] : 0.f;
    }
    // stage y + constant column
    for (int n = tid; n < NB; n += THR1) {
      int gn = n0 + n;
      Xs[n][49] = (gn < Nn) ? Yd[gn] : 0.f;
      Xs[n][40] = 1.f;
    }
    __syncthreads();
    // ELM hidden layer: h = sigmoid(x W + b)
    for (int idx = tid; idx < NB * Hh; idx += THR1) {
      int n = idx / Hh, h = idx % Hh;
      float z = sb[h];
#pragma unroll
      for (int d = 0; d < Dd; ++d) z += Xs[n][41 + d] * sW[d * Hh + h];
      Xs[n][h] = 1.f / (1.f + __expf(-z));
    }
    __syncthreads();
    // accumulate: acc[p][t] += phi[n][t] * Xe[n][i] * Xe[n][j]
    for (int n = 0; n < NB; ++n) {
      v16f ph = *(const v16f*)(&Ps[n][0]);  // 64B broadcast read
      float p0 = Xs[n][i0] * Xs[n][j0];
      float p1 = Xs[n][i1] * Xs[n][j1];
      float p2 = Xs[n][i2] * Xs[n][j2];
#pragma unroll
      for (int t = 0; t < Tt; ++t) {
        A0[t] = fmaf(p0, ph[t], A0[t]);
        A1[t] = fmaf(p1, ph[t], A1[t]);
        A2[t] = fmaf(p2, ph[t], A2[t]);
      }
    }
  }
  // flush partials: plain coalesced 64B vector stores into this block's slab
  float* slab = ws + (size_t)blockIdx.x * SLAB;
  if (v0) *(v16f*)(slab + (size_t)tid * Tt) = A0;
  if (v1) *(v16f*)(slab + (size_t)(tid + THR1) * Tt) = A1;
  if (v2) *(v16f*)(slab + (size_t)(tid + 2 * THR1) * Tt) = A2;
}

// ---------------- Kernel 1b: reduce slabs ----------------
__global__ __launch_bounds__(256)
void reduce_slabs(const float* __restrict__ ws, float* __restrict__ accout)
{
  int idx = blockIdx.x * 256 + threadIdx.x;
  if (idx >= NPAIR * Tt) return;
  float s = 0.f;
#pragma unroll 8
  for (int b = 0; b < SLABS; ++b) s += ws[(size_t)b * SLAB + idx];
  accout[idx] = s;
}

// ---------------- Kernel 2: per-t inversion + all small outputs ----------------
__global__ __launch_bounds__(256)
void finalize_kernel(const float* __restrict__ acc, const float* __restrict__ epsA,
                     const float* __restrict__ epsB, const float* __restrict__ zetA,
                     const float* __restrict__ zetB, float* __restrict__ out)
{
  int t = blockIdx.x;
  int tid = threadIdx.x;
  __shared__ float G[HP1][2 * HP1 + 2];   // augmented [M | I] -> [junk | WS]
  __shared__ float As[HP1][HP1 + 1];
  __shared__ float bs[HP1];
  __shared__ float colk[HP1];
  __shared__ float red[256];
  __shared__ float wmv[HP1];
  __shared__ float mus[Dd];
  __shared__ float pivinv_s;

  float epsExp = epsA[t] / epsB[t];
  float zetaExp = zetA[t] / zetB[t];

  for (int idx = tid; idx < HP1 * HP1; idx += 256) {
    int i = idx / HP1, j = idx % HP1;
    float a = acc[pidx(i, j) * Tt + t];
    As[i][j] = a;
    G[i][j] = epsExp * a + (i == j ? zetaExp : 0.f);
    G[i][HP1 + j] = (i == j) ? 1.f : 0.f;
  }
  if (tid < HP1) bs[tid] = acc[pidx(tid, 49) * Tt + t];
  __syncthreads();

  // Gauss-Jordan (SPD, no pivoting)
  for (int k = 0; k < HP1; ++k) {
    if (tid == 0) pivinv_s = 1.f / G[k][k];
    __syncthreads();
    float pivinv = pivinv_s;
    for (int j = tid; j < 2 * HP1; j += 256) G[k][j] *= pivinv;
    if (tid < HP1) colk[tid] = (tid == k) ? 0.f : G[tid][k];
    __syncthreads();
    for (int idx = tid; idx < HP1 * 2 * HP1; idx += 256) {
      int i = idx / (2 * HP1), j = idx % (2 * HP1);
      if (i != k) G[i][j] -= colk[i] * G[k][j];
    }
    __syncthreads();
  }

  // write WS
  for (int idx = tid; idx < HP1 * HP1; idx += 256) {
    int i = idx / HP1, j = idx % HP1;
    out[OFF_WS + (t * HP1 + i) * HP1 + j] = G[i][HP1 + j];
  }
  // WMv = zetaExp * WS @ b
  if (tid < HP1) {
    float s = 0.f;
    for (int j = 0; j < HP1; ++j) s += G[tid][HP1 + j] * bs[j];
    float w = zetaExp * s;
    wmv[tid] = w;
    out[OFF_WM + t * HP1 + tid] = w;
  }
  __syncthreads();
  // t2 = sum_ij A_ij * WS_ij  (both symmetric)
  float lt2 = 0.f;
  for (int idx = tid; idx < HP1 * HP1; idx += 256) {
    int i = idx / HP1, j = idx % HP1;
    lt2 += As[i][j] * G[i][HP1 + j];
  }
  red[tid] = lt2; __syncthreads();
  for (int s = 128; s > 0; s >>= 1) {
    if (tid < s) red[tid] += red[tid + s];
    __syncthreads();
  }
  float t2v = red[0];

  float sp = acc[pidx(40, 40) * Tt + t];  // sumPhi[t]
  float kap = 1000.f + sp;

  if (tid == 0) {
    float trWS = 0.f, wn = 0.f;
    for (int i = 0; i < HP1; ++i) { trWS += G[i][HP1 + i]; wn += wmv[i] * wmv[i]; }
    out[OFF_BG1 + t] = 1.f + sp;
    float rest = 0.f;
    for (int u = t + 1; u < Tt; ++u) rest += acc[pidx(40, 40) * Tt + u];
    out[OFF_BG2 + t] = 1.f + rest;            // ALPHA_DP = 1
    out[OFF_KAPPA + t] = kap;
    out[OFF_NU + t] = sp + 100.f;             // sumPhi + NU0
    out[OFF_ZA + t] = zetA[t] + 0.5f * (float)HP1;
    out[OFF_ZB + t] = zetB[t] + 0.5f * (wn + trWS);
    out[OFF_EA + t] = epsA[t] + 0.5f * sp;
    out[OFF_EB + t] = epsB[t] + 0.5f * t2v;   // kernel 3 atomically adds 0.5*t1
  }
  // mu
  if (tid < Dd) {
    float m = acc[pidx(40, 41 + tid) * Tt + t] / kap;
    mus[tid] = m;
    out[OFF_MU + tid * Tt + t] = m;
  }
  __syncthreads();
  // psi = 500*I + S - kappa * mu mu^T
  if (tid < Dd * Dd) {
    int i = tid / Dd, j = tid % Dd;
    float S = acc[pidx(41 + i, 41 + j) * Tt + t];
    float v = (i == j ? 500.f : 0.f) + S - kap * mus[i] * mus[j];
    out[OFF_PSI + (i * Dd + j) * Tt + t] = v;
  }
}

// ---------------- Kernel 3: t1 = sum_n phi * err^2 (LDS-tiled, no reg arrays) ----------------
__global__ __launch_bounds__(256, 2)
void resid_kernel(const float* __restrict__ Phi, const float* __restrict__ Xd,
                  const float* __restrict__ Yd, const float* __restrict__ Welm,
                  const float* __restrict__ belm, float* __restrict__ out)
{
  __shared__ float sW[Dd * Hh];
  __shared__ float sb[Hh];
  __shared__ float sWM[Tt][HP1];
  __shared__ float Xs[NB][XE];
  __shared__ float Ps[NB][Tt];
  __shared__ float red[256];

  int tid = threadIdx.x;
  for (int i = tid; i < Dd * Hh; i += 256) sW[i] = Welm[i];
  if (tid < Hh) sb[tid] = belm[tid];
  for (int i = tid; i < Tt * HP1; i += 256) sWM[i / HP1][i % HP1] = out[OFF_WM + i];

  int myt = tid & 15;   // invariant t for all 4 cells of this thread
  float acc = 0.f;

  for (int tile = blockIdx.x; tile < NTILES; tile += gridDim.x) {
    int n0 = tile * NB;
    __syncthreads();
    // stage phi
    for (int idx = tid; idx < NB * Tt; idx += 256) {
      int n = idx / Tt, t = idx % Tt;
      int gn = n0 + n;
      Ps[n][t] = (gn < Nn) ? Phi[gn * Tt + t] : 0.f;
    }
    // stage x
    for (int idx = tid; idx < NB * Dd; idx += 256) {
      int n = idx / Dd, d = idx % Dd;
      int gn = n0 + n;
      Xs[n][41 + d] = (gn < Nn) ? Xd[gn * Dd + d] : 0.f;
    }
    // stage y + const col
    for (int n = tid; n < NB; n += 256) {
      int gn = n0 + n;
      Xs[n][49] = (gn < Nn) ? Yd[gn] : 0.f;
      Xs[n][40] = 1.f;
    }
    __syncthreads();
    // ELM hidden layer
    for (int idx = tid; idx < NB * Hh; idx += 256) {
      int n = idx / Hh, h = idx % Hh;
      float z = sb[h];
#pragma unroll
      for (int d = 0; d < Dd; ++d) z += Xs[n][41 + d] * sW[d * Hh + h];
      Xs[n][h] = 1.f / (1.f + __expf(-z));
    }
    __syncthreads();
    // 1024 (n,t) cells, 4 per thread; t = tid&15 for all of them
#pragma unroll
    for (int k = 0; k < 4; ++k) {
      int n = (tid >> 4) + 16 * k;
      float pred = 0.f;
#pragma unroll
      for (int i = 0; i < HP1; ++i) pred = fmaf(Xs[n][i], sWM[myt][i], pred);
      float e = Xs[n][49] - pred;
      acc = fmaf(e * e, Ps[n][myt], acc);
    }
  }
  // block reduction per t: thread tid holds partial for t = tid&15
  red[tid] = acc;
  __syncthreads();
  if (tid < 16) {
    float s = 0.f;
#pragma unroll
    for (int j = 0; j < 16; ++j) s += red[tid + 16 * j];
    atomicAdd(&out[OFF_EB + tid], 0.5f * s);
  }
}

extern "C" void kernel_launch(void* const* d_in, const int* in_sizes, int n_in,
                              void* d_out, int out_size, void* d_ws, size_t ws_size,
                              hipStream_t stream) {
  const float* Phi = (const float*)d_in[1];
  const float* Xd  = (const float*)d_in[2];
  const float* Yd  = (const float*)d_in[3];
  const float* W   = (const float*)d_in[4];
  const float* bb  = (const float*)d_in[5];
  const float* eA  = (const float*)d_in[6];
  const float* eB  = (const float*)d_in[7];
  const float* zA  = (const float*)d_in[8];
  const float* zB  = (const float*)d_in[9];
  float* out = (float*)d_out;
  float* ws  = (float*)d_ws;
  float* acc_red = ws + (size_t)SLABS * SLAB;  // reduced Gram lives after the slabs

  hipLaunchKernelGGL(gram_reduce, dim3(GRID1), dim3(THR1), 0, stream, Phi, Xd, Yd, W, bb, ws);
  hipLaunchKernelGGL(reduce_slabs, dim3((NPAIR * Tt + 255) / 256), dim3(256), 0, stream, ws, acc_red);
  hipLaunchKernelGGL(finalize_kernel, dim3(Tt), dim3(256), 0, stream, acc_red, eA, eB, zA, zB, out);
  hipLaunchKernelGGL(resid_kernel, dim3(256), dim3(256), 0, stream, Phi, Xd, Yd, W, bb, out);
}